// Round 2
// baseline (479.799 us; speedup 1.0000x reference)
//
#include <hip/hip_runtime.h>
#include <hip/hip_bf16.h>

#define H_   16
#define NQ_  2048
#define NK_  2048
#define DM_  1024

typedef float f32x4 __attribute__((ext_vector_type(4)));
typedef __bf16 bf16x8 __attribute__((ext_vector_type(8)));
typedef unsigned short u16x8 __attribute__((ext_vector_type(8)));

__device__ __forceinline__ unsigned short f2bf(float x) {
  unsigned int u = __builtin_bit_cast(unsigned int, x);
  unsigned int r = (u + 0x7fffu + ((u >> 16) & 1u)) >> 16;
  return (unsigned short)r;
}
__device__ __forceinline__ float bf2f(unsigned short h) {
  unsigned int u = ((unsigned int)h) << 16;
  return __builtin_bit_cast(float, u);
}

// ---------------- prep: f32 -> bf16 bulk convert (8 elems/thread) ----------------
__global__ __launch_bounds__(256) void cvt_f32_bf16(const float* __restrict__ src,
                                                    unsigned short* __restrict__ dst, int n8) {
  int i = blockIdx.x * 256 + threadIdx.x;
  if (i >= n8) return;
  const float4* s4 = (const float4*)src;
  float4 a = s4[2 * i], b = s4[2 * i + 1];
  u16x8 o;
  o[0] = f2bf(a.x); o[1] = f2bf(a.y); o[2] = f2bf(a.z); o[3] = f2bf(a.w);
  o[4] = f2bf(b.x); o[5] = f2bf(b.y); o[6] = f2bf(b.z); o[7] = f2bf(b.w);
  *((u16x8*)dst + i) = o;
}

// ---------------- prep: transpose 1024x1024 f32 -> bf16 (SPLIT=1: Wo -> [hi,hi,lo] x3K) ----
template <int SPLIT>
__global__ __launch_bounds__(256) void transpose_cvt(const float* __restrict__ src,
                                                     unsigned short* __restrict__ dst) {
  __shared__ float t[64][65];
  const int r0 = blockIdx.x * 64, c0 = blockIdx.y * 64;
  for (int i = threadIdx.x; i < 4096; i += 256) {
    int r = i >> 6, c = i & 63;
    t[r][c] = src[(size_t)(r0 + r) * DM_ + c0 + c];
  }
  __syncthreads();
  for (int i = threadIdx.x; i < 4096; i += 256) {
    int n = i >> 6, k = i & 63;
    float w = t[k][n];
    if (!SPLIT) {
      dst[(size_t)(c0 + n) * DM_ + r0 + k] = f2bf(w);
    } else {
      unsigned short hi = f2bf(w);
      float lo = w - bf2f(hi);
      size_t base = (size_t)(c0 + n) * (3 * DM_) + r0 + k;
      dst[base] = hi;
      dst[base + DM_] = hi;
      dst[base + 2 * DM_] = f2bf(lo);
    }
  }
}

// ---------------- bf16 GEMM, 128x128 tile, BK=32, global_load_lds staging ----------------
__device__ __forceinline__ void gll16(const unsigned short* g, unsigned short* l) {
  __builtin_amdgcn_global_load_lds((const __attribute__((address_space(1))) void*)g,
                                   (__attribute__((address_space(3))) void*)l, 16, 0, 0);
}

// MODE 0: Q proj -> Qp, val=(acc+bq)*0.125*log2e (folds softmax exp2 base change)
// MODE 1: K proj -> Kp, val=(acc+bk)*gate
// MODE 2: V proj^T -> VpT, val=(acc+bv)*gate
// MODE 3: out proj -> f32 d_out
template <int MODE>
__global__ __launch_bounds__(256) void gemm_bf16(
    const unsigned short* __restrict__ A, const unsigned short* __restrict__ Bt, int K,
    const float* __restrict__ bias, const float* __restrict__ mem,
    const float* __restrict__ Wmm, const float* __restrict__ bmm,
    unsigned short* __restrict__ obf, float* __restrict__ of32) {
  __shared__ unsigned short Al[128 * 32];
  __shared__ unsigned short Bl[128 * 32];
  const int tid = threadIdx.x, lane = tid & 63, w = tid >> 6;
  const int wm = w >> 1, wn = w & 1;
  const int m0 = blockIdx.x * 128, n0 = blockIdx.y * 128;
  const int lrow = lane >> 2, lcol = (lane & 3) * 8;
  const int fr = lane & 15, fk = (lane >> 4) * 8;

  f32x4 acc[4][4] = {};

  const unsigned short* ag0 = A + (size_t)(m0 + w * 32 + lrow) * K + lcol;
  const unsigned short* bg0 = Bt + (size_t)(n0 + w * 32 + lrow) * K + lcol;
  unsigned short* la0 = &Al[(w * 32) * 32];
  unsigned short* la1 = &Al[(w * 32 + 16) * 32];
  unsigned short* lb0 = &Bl[(w * 32) * 32];
  unsigned short* lb1 = &Bl[(w * 32 + 16) * 32];
  const size_t s16K = (size_t)16 * K;

  const int KT = K >> 5;
  for (int kt = 0; kt < KT; ++kt) {
    gll16(ag0, la0); gll16(ag0 + s16K, la1);
    gll16(bg0, lb0); gll16(bg0 + s16K, lb1);
    ag0 += 32; bg0 += 32;
    __syncthreads();
    bf16x8 af[4], bfr[4];
#pragma unroll
    for (int i = 0; i < 4; ++i) af[i] = *(const bf16x8*)&Al[(wm * 64 + i * 16 + fr) * 32 + fk];
#pragma unroll
    for (int j = 0; j < 4; ++j) bfr[j] = *(const bf16x8*)&Bl[(wn * 64 + j * 16 + fr) * 32 + fk];
#pragma unroll
    for (int i = 0; i < 4; ++i)
#pragma unroll
      for (int j = 0; j < 4; ++j)
        acc[i][j] = __builtin_amdgcn_mfma_f32_16x16x32_bf16(af[i], bfr[j], acc[i][j], 0, 0, 0);
    __syncthreads();
  }

#pragma unroll
  for (int i = 0; i < 4; ++i) {
    const int rowb = m0 + wm * 64 + i * 16 + (lane >> 4) * 4;
#pragma unroll
    for (int j = 0; j < 4; ++j) {
      const int col = n0 + wn * 64 + j * 16 + fr;
#pragma unroll
      for (int r = 0; r < 4; ++r) {
        float v = acc[i][j][r];
        int rr = rowb + r;
        if (MODE == 0) {
          int b = rr >> 11, nq = rr & 2047, h = col >> 6, d = col & 63;
          float val = (v + bias[col]) * 0.180336884f;  // 0.125 * log2(e)
          obf[(((size_t)(b * H_ + h)) * NQ_ + nq) * 64 + d] = f2bf(val);
        } else if (MODE == 1) {
          int b = rr >> 11, nk = rr & 2047, h = col >> 6, d = col & 63;
          float gate = mem[b * NK_ + nk] * Wmm[col] + bmm[col];
          float val = (v + bias[col]) * gate;
          obf[(((size_t)(b * H_ + h)) * NK_ + nk) * 64 + d] = f2bf(val);
        } else if (MODE == 2) {
          int b = col >> 11, key = col & 2047, h = rr >> 6, d = rr & 63;
          float gate = mem[b * NK_ + key] * Wmm[rr] + bmm[rr];
          float val = (v + bias[rr]) * gate;
          obf[(((size_t)(b * H_ + h)) * 64 + d) * NK_ + key] = f2bf(val);
        } else {
          of32[(size_t)rr * DM_ + col] = v + bias[col];
        }
      }
    }
  }
}

// ---------------- flash attention v2: barrier-free, K/V from L2, Q in regs ----------------
// grid 1024 (XCD-swizzled), 4 waves/block, wave owns 16 q-rows. LDS = Ps only (9 KB).
__global__ __launch_bounds__(256) void flash_attn(const unsigned short* __restrict__ Qp,
                                                  const unsigned short* __restrict__ Kp,
                                                  const unsigned short* __restrict__ VpT,
                                                  unsigned short* __restrict__ AO2) {
  __shared__ __bf16 Ps[64][72];

  const int tid = threadIdx.x, lane = tid & 63, w = tid >> 6;
  // XCD-aware swizzle: 1024 blocks % 8 == 0 -> bijective chunked remap
  const int gid = (blockIdx.x & 7) * 128 + (blockIdx.x >> 3);
  const int bh = gid >> 5;       // 0..31
  const int qt = gid & 31;       // 0..31, Q-tile of 64 rows
  const int fr = lane & 15, fk8 = (lane >> 4) * 8;
  const int rbase = (lane >> 4) * 4;
  const int w16 = w * 16;

  // Q fragments hoisted to registers (loop-invariant)
  const unsigned short* qg = Qp + (((size_t)bh * NQ_) + qt * 64 + w16 + fr) * 64;
  bf16x8 aq[2];
  aq[0] = *(const bf16x8*)&qg[fk8];
  aq[1] = *(const bf16x8*)&qg[32 + fk8];

  f32x4 acc_o[4] = {};
  float m_run[4], l_run[4];
#pragma unroll
  for (int r = 0; r < 4; ++r) { m_run[r] = -1e30f; l_run[r] = 0.0f; }

  const unsigned short* kg0 = Kp + (((size_t)bh * NK_) + fr) * 64 + fk8;
  const unsigned short* vg0 = VpT + ((size_t)bh * 64 + fr) * NK_ + fk8;

  for (int kt = 0; kt < 32; ++kt) {
    // S^(base2) = Q K'^T : K fragments straight from global (L2-resident)
    f32x4 sv[4];
#pragma unroll
    for (int kk = 0; kk < 4; ++kk) {
      const unsigned short* kg = kg0 + ((size_t)(kt * 64 + kk * 16)) * 64;
      bf16x8 b0 = *(const bf16x8*)kg;
      bf16x8 b1 = *(const bf16x8*)(kg + 32);
      f32x4 z = {0.f, 0.f, 0.f, 0.f};
      z = __builtin_amdgcn_mfma_f32_16x16x32_bf16(aq[0], b0, z, 0, 0, 0);
      sv[kk] = __builtin_amdgcn_mfma_f32_16x16x32_bf16(aq[1], b1, z, 0, 0, 0);
    }

    // online softmax (base-2); rows live across 16-lane groups
    float mx[4];
#pragma unroll
    for (int r = 0; r < 4; ++r)
      mx[r] = fmaxf(fmaxf(sv[0][r], sv[1][r]), fmaxf(sv[2][r], sv[3][r]));
#pragma unroll
    for (int off = 1; off <= 8; off <<= 1)
#pragma unroll
      for (int r = 0; r < 4; ++r) mx[r] = fmaxf(mx[r], __shfl_xor(mx[r], off));
#pragma unroll
    for (int r = 0; r < 4; ++r) {
      if (mx[r] > m_run[r] + 8.0f) {  // defer-rescale: P bounded by 2^8
        float sc = __builtin_amdgcn_exp2f(m_run[r] - mx[r]);
        m_run[r] = mx[r];
        l_run[r] *= sc;
#pragma unroll
        for (int n = 0; n < 4; ++n) acc_o[n][r] *= sc;
      }
    }
    float ps[4] = {0.f, 0.f, 0.f, 0.f};
#pragma unroll
    for (int kk = 0; kk < 4; ++kk)
#pragma unroll
      for (int r = 0; r < 4; ++r) {
        float p = __builtin_amdgcn_exp2f(sv[kk][r] - m_run[r]);
        ps[r] += p;
        Ps[w16 + rbase + r][kk * 16 + fr] = (__bf16)p;  // wave-private rows
      }
#pragma unroll
    for (int off = 1; off <= 8; off <<= 1)
#pragma unroll
      for (int r = 0; r < 4; ++r) ps[r] += __shfl_xor(ps[r], off);
#pragma unroll
    for (int r = 0; r < 4; ++r) l_run[r] += ps[r];

    // O += P V' : P same-wave LDS (in-order, no barrier), V from global
#pragma unroll
    for (int ks = 0; ks < 2; ++ks) {
      bf16x8 pa = *(const bf16x8*)&Ps[w16 + fr][ks * 32 + fk8];
#pragma unroll
      for (int n = 0; n < 4; ++n) {
        bf16x8 vb = *(const bf16x8*)(vg0 + (size_t)(n * 16) * NK_ + kt * 64 + ks * 32);
        acc_o[n] = __builtin_amdgcn_mfma_f32_16x16x32_bf16(pa, vb, acc_o[n], 0, 0, 0);
      }
    }
  }

  // epilogue: normalize, split hi/lo, write AO2 (4096 x 3072) = [hi | lo | hi]
  const int b = bh >> 4, h = bh & 15;
  float linv[4];
#pragma unroll
  for (int r = 0; r < 4; ++r) linv[r] = 1.0f / l_run[r];
#pragma unroll
  for (int n = 0; n < 4; ++n)
#pragma unroll
    for (int r = 0; r < 4; ++r) {
      float val = acc_o[n][r] * linv[r];
      int qrow = qt * 64 + w16 + rbase + r;
      int col = h * 64 + n * 16 + fr;
      size_t base = ((size_t)b * NQ_ + qrow) * 3072;
      __bf16 hb = (__bf16)val;
      float lo = val - (float)hb;
      unsigned short hi = __builtin_bit_cast(unsigned short, hb);
      AO2[base + col] = hi;
      AO2[base + 1024 + col] = f2bf(lo);
      AO2[base + 2048 + col] = hi;
    }
}

extern "C" void kernel_launch(void* const* d_in, const int* in_sizes, int n_in,
                              void* d_out, int out_size, void* d_ws, size_t ws_size,
                              hipStream_t stream) {
  const float* queries = (const float*)d_in[0];
  const float* keys    = (const float*)d_in[1];
  const float* values  = (const float*)d_in[2];
  const float* memory  = (const float*)d_in[3];
  const float* Wq  = (const float*)d_in[4];
  const float* bq  = (const float*)d_in[5];
  const float* Wk  = (const float*)d_in[6];
  const float* bk  = (const float*)d_in[7];
  const float* Wv  = (const float*)d_in[8];
  const float* bv  = (const float*)d_in[9];
  const float* Wo  = (const float*)d_in[10];
  const float* bo  = (const float*)d_in[11];
  const float* Wmm = (const float*)d_in[12];
  const float* bmm = (const float*)d_in[13];

  char* ws = (char*)d_ws;
  const size_t SZ_X = (size_t)4096 * 1024 * 2;  // 8 MiB per bf16 input copy
  unsigned short* qbf = (unsigned short*)(ws);
  unsigned short* kbf = (unsigned short*)(ws + SZ_X);
  unsigned short* vbf = (unsigned short*)(ws + 2 * SZ_X);
  unsigned short* AO2 = (unsigned short*)(ws);  // 4096x3072, aliases qbf/kbf/vbf (dead by then)
  size_t off = 3 * SZ_X;
  unsigned short* WqT  = (unsigned short*)(ws + off); off += (size_t)1024 * 1024 * 2;
  unsigned short* WkT  = (unsigned short*)(ws + off); off += (size_t)1024 * 1024 * 2;
  unsigned short* WvT  = (unsigned short*)(ws + off); off += (size_t)1024 * 1024 * 2;
  unsigned short* WoT2 = (unsigned short*)(ws + off); off += (size_t)1024 * 3072 * 2;
  unsigned short* Qp   = (unsigned short*)(ws + off); off += SZ_X;
  unsigned short* Kp   = (unsigned short*)(ws + off); off += SZ_X;
  unsigned short* VpT  = (unsigned short*)(ws + off); off += SZ_X;

  const int n8 = 4096 * 1024 / 8;
  cvt_f32_bf16<<<2048, 256, 0, stream>>>(queries, qbf, n8);
  cvt_f32_bf16<<<2048, 256, 0, stream>>>(keys, kbf, n8);
  cvt_f32_bf16<<<2048, 256, 0, stream>>>(values, vbf, n8);
  transpose_cvt<0><<<dim3(16, 16), 256, 0, stream>>>(Wq, WqT);
  transpose_cvt<0><<<dim3(16, 16), 256, 0, stream>>>(Wk, WkT);
  transpose_cvt<0><<<dim3(16, 16), 256, 0, stream>>>(Wv, WvT);
  transpose_cvt<1><<<dim3(16, 16), 256, 0, stream>>>(Wo, WoT2);

  gemm_bf16<0><<<dim3(32, 8), 256, 0, stream>>>(qbf, WqT, 1024, bq, nullptr, nullptr, nullptr, Qp, nullptr);
  gemm_bf16<1><<<dim3(32, 8), 256, 0, stream>>>(kbf, WkT, 1024, bk, memory, Wmm, bmm, Kp, nullptr);
  gemm_bf16<2><<<dim3(8, 32), 256, 0, stream>>>(WvT, vbf, 1024, bv, memory, Wmm, bmm, VpT, nullptr);

  flash_attn<<<1024, 256, 0, stream>>>(Qp, Kp, VpT, AO2);

  gemm_bf16<3><<<dim3(32, 8), 256, 0, stream>>>(AO2, WoT2, 3072, bo, nullptr, nullptr, nullptr,
                                                nullptr, (float*)d_out);
}

// Round 3
// 267.830 us; speedup vs baseline: 1.7914x; 1.7914x over previous
//
#include <hip/hip_runtime.h>
#include <hip/hip_bf16.h>

#define H_   16
#define NQ_  2048
#define NK_  2048
#define DM_  1024

typedef float f32x4 __attribute__((ext_vector_type(4)));
typedef __bf16 bf16x8 __attribute__((ext_vector_type(8)));
typedef unsigned short u16x8 __attribute__((ext_vector_type(8)));

__device__ __forceinline__ unsigned short f2bf(float x) {
  unsigned int u = __builtin_bit_cast(unsigned int, x);
  unsigned int r = (u + 0x7fffu + ((u >> 16) & 1u)) >> 16;
  return (unsigned short)r;
}
__device__ __forceinline__ float bf2f(unsigned short h) {
  unsigned int u = ((unsigned int)h) << 16;
  return __builtin_bit_cast(float, u);
}

// ---------------- prep: f32 -> bf16 bulk convert (8 elems/thread) ----------------
__global__ __launch_bounds__(256) void cvt_f32_bf16(const float* __restrict__ src,
                                                    unsigned short* __restrict__ dst, int n8) {
  int i = blockIdx.x * 256 + threadIdx.x;
  if (i >= n8) return;
  const float4* s4 = (const float4*)src;
  float4 a = s4[2 * i], b = s4[2 * i + 1];
  u16x8 o;
  o[0] = f2bf(a.x); o[1] = f2bf(a.y); o[2] = f2bf(a.z); o[3] = f2bf(a.w);
  o[4] = f2bf(b.x); o[5] = f2bf(b.y); o[6] = f2bf(b.z); o[7] = f2bf(b.w);
  *((u16x8*)dst + i) = o;
}

// ---------------- prep: transpose 1024x1024 f32 -> bf16 (SPLIT=1: Wo -> [hi,hi,lo] x3K) ----
template <int SPLIT>
__global__ __launch_bounds__(256) void transpose_cvt(const float* __restrict__ src,
                                                     unsigned short* __restrict__ dst) {
  __shared__ float t[64][65];
  const int r0 = blockIdx.x * 64, c0 = blockIdx.y * 64;
  for (int i = threadIdx.x; i < 4096; i += 256) {
    int r = i >> 6, c = i & 63;
    t[r][c] = src[(size_t)(r0 + r) * DM_ + c0 + c];
  }
  __syncthreads();
  for (int i = threadIdx.x; i < 4096; i += 256) {
    int n = i >> 6, k = i & 63;
    float w = t[k][n];
    if (!SPLIT) {
      dst[(size_t)(c0 + n) * DM_ + r0 + k] = f2bf(w);
    } else {
      unsigned short hi = f2bf(w);
      float lo = w - bf2f(hi);
      size_t base = (size_t)(c0 + n) * (3 * DM_) + r0 + k;
      dst[base] = hi;
      dst[base + DM_] = hi;
      dst[base + 2 * DM_] = f2bf(lo);
    }
  }
}

// ---------------- bf16 GEMM, 64x128 tile, BK=32, global_load_lds staging ----------------
// grid (M/64, N/128) -> 512 blocks for all modes = 2 blocks/CU (was 1: no overlap).
__device__ __forceinline__ void gll16(const unsigned short* g, unsigned short* l) {
  __builtin_amdgcn_global_load_lds((const __attribute__((address_space(1))) void*)g,
                                   (__attribute__((address_space(3))) void*)l, 16, 0, 0);
}

// MODE 0: Q proj -> Qp, val=(acc+bq)*0.125*log2e (folds softmax exp2 base change)
// MODE 1: K proj -> Kp, val=(acc+bk)*gate
// MODE 2: V proj^T -> VpT, val=(acc+bv)*gate
// MODE 3: out proj -> f32 d_out
template <int MODE>
__global__ __launch_bounds__(256) void gemm_bf16(
    const unsigned short* __restrict__ A, const unsigned short* __restrict__ Bt, int K,
    const float* __restrict__ bias, const float* __restrict__ mem,
    const float* __restrict__ Wmm, const float* __restrict__ bmm,
    unsigned short* __restrict__ obf, float* __restrict__ of32) {
  __shared__ unsigned short Al[64 * 32];
  __shared__ unsigned short Bl[128 * 32];
  const int tid = threadIdx.x, lane = tid & 63, w = tid >> 6;
  const int wm = w >> 1, wn = w & 1;
  const int m0 = blockIdx.x * 64, n0 = blockIdx.y * 128;
  const int lrow = lane >> 2, lcol = (lane & 3) * 8;
  const int fr = lane & 15, fk = (lane >> 4) * 8;

  f32x4 acc[2][4] = {};

  const unsigned short* ag0 = A + (size_t)(m0 + w * 16 + lrow) * K + lcol;
  const unsigned short* bg0 = Bt + (size_t)(n0 + w * 32 + lrow) * K + lcol;
  unsigned short* la0 = &Al[(w * 16) * 32];
  unsigned short* lb0 = &Bl[(w * 32) * 32];
  unsigned short* lb1 = &Bl[(w * 32 + 16) * 32];
  const size_t s16K = (size_t)16 * K;

  const int KT = K >> 5;
  for (int kt = 0; kt < KT; ++kt) {
    gll16(ag0, la0);
    gll16(bg0, lb0); gll16(bg0 + s16K, lb1);
    ag0 += 32; bg0 += 32;
    __syncthreads();
    bf16x8 af[2], bfr[4];
#pragma unroll
    for (int i = 0; i < 2; ++i) af[i] = *(const bf16x8*)&Al[(wm * 32 + i * 16 + fr) * 32 + fk];
#pragma unroll
    for (int j = 0; j < 4; ++j) bfr[j] = *(const bf16x8*)&Bl[(wn * 64 + j * 16 + fr) * 32 + fk];
#pragma unroll
    for (int i = 0; i < 2; ++i)
#pragma unroll
      for (int j = 0; j < 4; ++j)
        acc[i][j] = __builtin_amdgcn_mfma_f32_16x16x32_bf16(af[i], bfr[j], acc[i][j], 0, 0, 0);
    __syncthreads();
  }

#pragma unroll
  for (int i = 0; i < 2; ++i) {
    const int rowb = m0 + wm * 32 + i * 16 + (lane >> 4) * 4;
#pragma unroll
    for (int j = 0; j < 4; ++j) {
      const int col = n0 + wn * 64 + j * 16 + fr;
#pragma unroll
      for (int r = 0; r < 4; ++r) {
        float v = acc[i][j][r];
        int rr = rowb + r;
        if (MODE == 0) {
          int b = rr >> 11, nq = rr & 2047, h = col >> 6, d = col & 63;
          float val = (v + bias[col]) * 0.180336884f;  // 0.125 * log2(e)
          obf[(((size_t)(b * H_ + h)) * NQ_ + nq) * 64 + d] = f2bf(val);
        } else if (MODE == 1) {
          int b = rr >> 11, nk = rr & 2047, h = col >> 6, d = col & 63;
          float gate = mem[b * NK_ + nk] * Wmm[col] + bmm[col];
          float val = (v + bias[col]) * gate;
          obf[(((size_t)(b * H_ + h)) * NK_ + nk) * 64 + d] = f2bf(val);
        } else if (MODE == 2) {
          int b = col >> 11, key = col & 2047, h = rr >> 6, d = rr & 63;
          float gate = mem[b * NK_ + key] * Wmm[rr] + bmm[rr];
          float val = (v + bias[rr]) * gate;
          obf[(((size_t)(b * H_ + h)) * 64 + d) * NK_ + key] = f2bf(val);
        } else {
          of32[(size_t)rr * DM_ + col] = v + bias[col];
        }
      }
    }
  }
}

// ---------------- flash attention v3: LDS-staged K/V, double-buffered, 1 barrier/tile ----
// 512 blocks x 8 waves; block owns 128 q-rows (wave: 16), KV-tile 64.
// T14: issue tile t+1 global loads before barrier, ds_write after compute.
__global__ __launch_bounds__(512, 4) void flash_attn(const unsigned short* __restrict__ Qp,
                                                     const unsigned short* __restrict__ Kp,
                                                     const unsigned short* __restrict__ VpT,
                                                     unsigned short* __restrict__ AO2) {
  __shared__ unsigned short Ks[2][64][72];
  __shared__ unsigned short Vs[2][64][72];
  __shared__ __bf16 Ps[128][72];

  const int tid = threadIdx.x, lane = tid & 63, w = tid >> 6;
  // XCD-aware swizzle: 512 blocks % 8 == 0 -> bijective chunked remap
  const int gid = (blockIdx.x & 7) * 64 + (blockIdx.x >> 3);
  const int bh = gid >> 4;       // 0..31
  const int qt = gid & 15;       // 0..15, Q-tile of 128 rows
  const int fr = lane & 15, fk8 = (lane >> 4) * 8;
  const int rbase = (lane >> 4) * 4;
  const int w16 = w * 16;

  // Q fragments hoisted to registers (loop-invariant)
  const unsigned short* qg = Qp + (((size_t)bh * NQ_) + qt * 128 + w16 + fr) * 64;
  bf16x8 aq0 = *(const bf16x8*)&qg[fk8];
  bf16x8 aq1 = *(const bf16x8*)&qg[32 + fk8];

  // staging addresses: thread loads one u16x8 of K and one of V^T per tile
  const int srow = tid >> 3, scol = (tid & 7) * 8;
  const unsigned short* kg = Kp + ((size_t)bh * NK_ + srow) * 64 + scol;
  const unsigned short* vg = VpT + ((size_t)bh * 64 + srow) * NK_ + scol;

  f32x4 acc_o[4] = {};
  float m_run[4], l_run[4];
#pragma unroll
  for (int r = 0; r < 4; ++r) { m_run[r] = -1e30f; l_run[r] = 0.0f; }

  // prologue: stage tile 0
  {
    u16x8 k0 = *(const u16x8*)kg;
    u16x8 v0 = *(const u16x8*)vg;
    *(u16x8*)&Ks[0][srow][scol] = k0;
    *(u16x8*)&Vs[0][srow][scol] = v0;
  }

  u16x8 kreg, vreg;
  for (int kt = 0; kt < 32; ++kt) {
    const int cur = kt & 1;
    if (kt + 1 < 32) {  // issue next-tile loads early (latency hides under compute)
      kreg = *(const u16x8*)(kg + (kt + 1) * 64 * 64);
      vreg = *(const u16x8*)(vg + (kt + 1) * 64);
    }
    __syncthreads();  // buf[cur] writes visible; prior reads of buf[cur^1] done

    // S^(base2) = Q K'^T
    f32x4 sv[4];
    __builtin_amdgcn_s_setprio(1);
#pragma unroll
    for (int kk = 0; kk < 4; ++kk) {
      bf16x8 b0 = *(const bf16x8*)&Ks[cur][kk * 16 + fr][fk8];
      bf16x8 b1 = *(const bf16x8*)&Ks[cur][kk * 16 + fr][32 + fk8];
      f32x4 z = {0.f, 0.f, 0.f, 0.f};
      z = __builtin_amdgcn_mfma_f32_16x16x32_bf16(aq0, b0, z, 0, 0, 0);
      sv[kk] = __builtin_amdgcn_mfma_f32_16x16x32_bf16(aq1, b1, z, 0, 0, 0);
    }
    __builtin_amdgcn_s_setprio(0);

    // online softmax (base-2); rows live across 16-lane groups
    float mx[4];
#pragma unroll
    for (int r = 0; r < 4; ++r)
      mx[r] = fmaxf(fmaxf(sv[0][r], sv[1][r]), fmaxf(sv[2][r], sv[3][r]));
#pragma unroll
    for (int off = 1; off <= 8; off <<= 1)
#pragma unroll
      for (int r = 0; r < 4; ++r) mx[r] = fmaxf(mx[r], __shfl_xor(mx[r], off));
#pragma unroll
    for (int r = 0; r < 4; ++r) {
      if (mx[r] > m_run[r] + 8.0f) {  // defer-rescale: P bounded by 2^8
        float sc = __builtin_amdgcn_exp2f(m_run[r] - mx[r]);
        m_run[r] = mx[r];
        l_run[r] *= sc;
#pragma unroll
        for (int n = 0; n < 4; ++n) acc_o[n][r] *= sc;
      }
    }
    float ps[4] = {0.f, 0.f, 0.f, 0.f};
#pragma unroll
    for (int kk = 0; kk < 4; ++kk)
#pragma unroll
      for (int r = 0; r < 4; ++r) {
        float p = __builtin_amdgcn_exp2f(sv[kk][r] - m_run[r]);
        ps[r] += p;
        Ps[w16 + rbase + r][kk * 16 + fr] = (__bf16)p;  // wave-private rows
      }
#pragma unroll
    for (int off = 1; off <= 8; off <<= 1)
#pragma unroll
      for (int r = 0; r < 4; ++r) ps[r] += __shfl_xor(ps[r], off);
#pragma unroll
    for (int r = 0; r < 4; ++r) l_run[r] += ps[r];

    // O += P V' : P same-wave LDS (in-order, no barrier)
    __builtin_amdgcn_s_setprio(1);
#pragma unroll
    for (int ks = 0; ks < 2; ++ks) {
      bf16x8 pa = *(const bf16x8*)&Ps[w16 + fr][ks * 32 + fk8];
#pragma unroll
      for (int n = 0; n < 4; ++n) {
        bf16x8 vb = *(const bf16x8*)&Vs[cur][n * 16 + fr][ks * 32 + fk8];
        acc_o[n] = __builtin_amdgcn_mfma_f32_16x16x32_bf16(pa, vb, acc_o[n], 0, 0, 0);
      }
    }
    __builtin_amdgcn_s_setprio(0);

    if (kt + 1 < 32) {  // write next tile (compiler inserts vmcnt wait here)
      *(u16x8*)&Ks[cur ^ 1][srow][scol] = kreg;
      *(u16x8*)&Vs[cur ^ 1][srow][scol] = vreg;
    }
  }

  // epilogue: normalize, split hi/lo, write AO2 (4096 x 3072) = [hi | lo | hi]
  const int b = bh >> 4, h = bh & 15;
  float linv[4];
#pragma unroll
  for (int r = 0; r < 4; ++r) linv[r] = 1.0f / l_run[r];
#pragma unroll
  for (int n = 0; n < 4; ++n)
#pragma unroll
    for (int r = 0; r < 4; ++r) {
      float val = acc_o[n][r] * linv[r];
      int qrow = qt * 128 + w16 + rbase + r;
      int col = h * 64 + n * 16 + fr;
      size_t base = ((size_t)b * NQ_ + qrow) * 3072;
      __bf16 hb = (__bf16)val;
      float lo = val - (float)hb;
      unsigned short hi = __builtin_bit_cast(unsigned short, hb);
      AO2[base + col] = hi;
      AO2[base + 1024 + col] = f2bf(lo);
      AO2[base + 2048 + col] = hi;
    }
}

extern "C" void kernel_launch(void* const* d_in, const int* in_sizes, int n_in,
                              void* d_out, int out_size, void* d_ws, size_t ws_size,
                              hipStream_t stream) {
  const float* queries = (const float*)d_in[0];
  const float* keys    = (const float*)d_in[1];
  const float* values  = (const float*)d_in[2];
  const float* memory  = (const float*)d_in[3];
  const float* Wq  = (const float*)d_in[4];
  const float* bq  = (const float*)d_in[5];
  const float* Wk  = (const float*)d_in[6];
  const float* bk  = (const float*)d_in[7];
  const float* Wv  = (const float*)d_in[8];
  const float* bv  = (const float*)d_in[9];
  const float* Wo  = (const float*)d_in[10];
  const float* bo  = (const float*)d_in[11];
  const float* Wmm = (const float*)d_in[12];
  const float* bmm = (const float*)d_in[13];

  char* ws = (char*)d_ws;
  const size_t SZ_X = (size_t)4096 * 1024 * 2;  // 8 MiB per bf16 input copy
  unsigned short* qbf = (unsigned short*)(ws);
  unsigned short* kbf = (unsigned short*)(ws + SZ_X);
  unsigned short* vbf = (unsigned short*)(ws + 2 * SZ_X);
  unsigned short* AO2 = (unsigned short*)(ws);  // 4096x3072, aliases qbf/kbf/vbf (dead by then)
  size_t off = 3 * SZ_X;
  unsigned short* WqT  = (unsigned short*)(ws + off); off += (size_t)1024 * 1024 * 2;
  unsigned short* WkT  = (unsigned short*)(ws + off); off += (size_t)1024 * 1024 * 2;
  unsigned short* WvT  = (unsigned short*)(ws + off); off += (size_t)1024 * 1024 * 2;
  unsigned short* WoT2 = (unsigned short*)(ws + off); off += (size_t)1024 * 3072 * 2;
  unsigned short* Qp   = (unsigned short*)(ws + off); off += SZ_X;
  unsigned short* Kp   = (unsigned short*)(ws + off); off += SZ_X;
  unsigned short* VpT  = (unsigned short*)(ws + off); off += SZ_X;

  const int n8 = 4096 * 1024 / 8;
  cvt_f32_bf16<<<2048, 256, 0, stream>>>(queries, qbf, n8);
  cvt_f32_bf16<<<2048, 256, 0, stream>>>(keys, kbf, n8);
  cvt_f32_bf16<<<2048, 256, 0, stream>>>(values, vbf, n8);
  transpose_cvt<0><<<dim3(16, 16), 256, 0, stream>>>(Wq, WqT);
  transpose_cvt<0><<<dim3(16, 16), 256, 0, stream>>>(Wk, WkT);
  transpose_cvt<0><<<dim3(16, 16), 256, 0, stream>>>(Wv, WvT);
  transpose_cvt<1><<<dim3(16, 16), 256, 0, stream>>>(Wo, WoT2);

  gemm_bf16<0><<<dim3(64, 8), 256, 0, stream>>>(qbf, WqT, 1024, bq, nullptr, nullptr, nullptr, Qp, nullptr);
  gemm_bf16<1><<<dim3(64, 8), 256, 0, stream>>>(kbf, WkT, 1024, bk, memory, Wmm, bmm, Kp, nullptr);
  gemm_bf16<2><<<dim3(16, 32), 256, 0, stream>>>(WvT, vbf, 1024, bv, memory, Wmm, bmm, VpT, nullptr);

  flash_attn<<<512, 512, 0, stream>>>(Qp, Kp, VpT, AO2);

  gemm_bf16<3><<<dim3(64, 8), 256, 0, stream>>>(AO2, WoT2, 3072, bo, nullptr, nullptr, nullptr,
                                                nullptr, (float*)d_out);
}

// Round 4
// 183.502 us; speedup vs baseline: 2.6147x; 1.4595x over previous
//
#include <hip/hip_runtime.h>
#include <hip/hip_bf16.h>

#define H_   16
#define NQ_  2048
#define NK_  2048
#define DM_  1024

typedef float f32x4 __attribute__((ext_vector_type(4)));
typedef __bf16 bf16x8 __attribute__((ext_vector_type(8)));
typedef unsigned short u16x8 __attribute__((ext_vector_type(8)));
typedef unsigned short u16x4 __attribute__((ext_vector_type(4)));

__device__ __forceinline__ unsigned short f2bf(float x) {
  unsigned int u = __builtin_bit_cast(unsigned int, x);
  unsigned int r = (u + 0x7fffu + ((u >> 16) & 1u)) >> 16;
  return (unsigned short)r;
}

// ---------------- prep: 4x fused transpose 1024x1024 f32 -> bf16 ----------------
__global__ __launch_bounds__(256) void transpose_cvt4(
    const float* __restrict__ s0, const float* __restrict__ s1,
    const float* __restrict__ s2, const float* __restrict__ s3,
    unsigned short* __restrict__ d0, unsigned short* __restrict__ d1,
    unsigned short* __restrict__ d2, unsigned short* __restrict__ d3) {
  const float* src = (blockIdx.z == 0) ? s0 : (blockIdx.z == 1) ? s1 : (blockIdx.z == 2) ? s2 : s3;
  unsigned short* dst = (blockIdx.z == 0) ? d0 : (blockIdx.z == 1) ? d1 : (blockIdx.z == 2) ? d2 : d3;
  __shared__ float t[64][65];
  const int r0 = blockIdx.x * 64, c0 = blockIdx.y * 64;
  for (int i = threadIdx.x; i < 4096; i += 256) {
    int r = i >> 6, c = i & 63;
    t[r][c] = src[(size_t)(r0 + r) * DM_ + c0 + c];
  }
  __syncthreads();
  for (int i = threadIdx.x; i < 4096; i += 256) {
    int n = i >> 6, k = i & 63;
    dst[(size_t)(c0 + n) * DM_ + r0 + k] = f2bf(t[k][n]);
  }
}

// ---------------- bf16 GEMM, 64x128 tile, BK=32 ----------------
// A or Bt may be f32 (converted during reg-staging); the bf16 operand uses global_load_lds.
__device__ __forceinline__ void gll16(const unsigned short* g, unsigned short* l) {
  __builtin_amdgcn_global_load_lds((const __attribute__((address_space(1))) void*)g,
                                   (__attribute__((address_space(3))) void*)l, 16, 0, 0);
}

// MODE 0: Q proj (A=queries f32) -> Qp, val=(acc+bq)*0.125*log2e
// MODE 1: K proj (A=keys f32)    -> Kp, val=(acc+bk)*gate
// MODE 2: V proj^T (A=WvT bf16, Bt=values f32) -> VpT, val=(acc+bv)*gate
// MODE 3: out proj (A=AO bf16)   -> f32 d_out, val=acc+bo
template <int MODE>
__global__ __launch_bounds__(256) void gemm_bf16(
    const void* __restrict__ Av, const void* __restrict__ Btv, int K,
    const float* __restrict__ bias, const float* __restrict__ mem,
    const float* __restrict__ Wmm, const float* __restrict__ bmm,
    unsigned short* __restrict__ obf, float* __restrict__ of32) {
  constexpr bool AF32 = (MODE <= 1);
  constexpr bool BF32 = (MODE == 2);
  __shared__ unsigned short Al[64 * 32];
  __shared__ unsigned short Bl[128 * 32];
  const int tid = threadIdx.x, lane = tid & 63, w = tid >> 6;
  const int wm = w >> 1, wn = w & 1;
  const int m0 = blockIdx.x * 64, n0 = blockIdx.y * 128;
  const int lrow = lane >> 2, lcol = (lane & 3) * 8;
  const int fr = lane & 15, fk = (lane >> 4) * 8;

  f32x4 acc[2][4] = {};

  const size_t aoff = (size_t)(m0 + w * 16 + lrow) * K + lcol;
  const size_t boff = (size_t)(n0 + w * 32 + lrow) * K + lcol;
  const unsigned short* ag = (const unsigned short*)Av + aoff;
  const float*          agf = (const float*)Av + aoff;
  const unsigned short* bg = (const unsigned short*)Btv + boff;
  const float*          bgf = (const float*)Btv + boff;
  unsigned short* la0 = &Al[(w * 16) * 32];
  unsigned short* lawr = &Al[(w * 16 + lrow) * 32 + lcol];
  unsigned short* lb0 = &Bl[(w * 32) * 32];
  unsigned short* lb1 = &Bl[(w * 32 + 16) * 32];
  unsigned short* lbwr0 = &Bl[(w * 32 + lrow) * 32 + lcol];
  unsigned short* lbwr1 = &Bl[(w * 32 + 16 + lrow) * 32 + lcol];
  const size_t s16K = (size_t)16 * K;

  const int KT = K >> 5;
  for (int kt = 0; kt < KT; ++kt) {
    if constexpr (AF32) {
      float4 x0 = *(const float4*)agf;
      float4 x1 = *(const float4*)(agf + 4);
      agf += 32;
      u16x8 o;
      o[0] = f2bf(x0.x); o[1] = f2bf(x0.y); o[2] = f2bf(x0.z); o[3] = f2bf(x0.w);
      o[4] = f2bf(x1.x); o[5] = f2bf(x1.y); o[6] = f2bf(x1.z); o[7] = f2bf(x1.w);
      *(u16x8*)lawr = o;
    } else {
      gll16(ag, la0);
      ag += 32;
    }
    if constexpr (BF32) {
      float4 y0 = *(const float4*)bgf;
      float4 y1 = *(const float4*)(bgf + 4);
      float4 y2 = *(const float4*)(bgf + s16K);
      float4 y3 = *(const float4*)(bgf + s16K + 4);
      bgf += 32;
      u16x8 o0, o1;
      o0[0] = f2bf(y0.x); o0[1] = f2bf(y0.y); o0[2] = f2bf(y0.z); o0[3] = f2bf(y0.w);
      o0[4] = f2bf(y1.x); o0[5] = f2bf(y1.y); o0[6] = f2bf(y1.z); o0[7] = f2bf(y1.w);
      o1[0] = f2bf(y2.x); o1[1] = f2bf(y2.y); o1[2] = f2bf(y2.z); o1[3] = f2bf(y2.w);
      o1[4] = f2bf(y3.x); o1[5] = f2bf(y3.y); o1[6] = f2bf(y3.z); o1[7] = f2bf(y3.w);
      *(u16x8*)lbwr0 = o0;
      *(u16x8*)lbwr1 = o1;
    } else {
      gll16(bg, lb0);
      gll16(bg + s16K, lb1);
      bg += 32;
    }
    __syncthreads();
    bf16x8 af[2], bfr[4];
#pragma unroll
    for (int i = 0; i < 2; ++i) af[i] = *(const bf16x8*)&Al[(wm * 32 + i * 16 + fr) * 32 + fk];
#pragma unroll
    for (int j = 0; j < 4; ++j) bfr[j] = *(const bf16x8*)&Bl[(wn * 64 + j * 16 + fr) * 32 + fk];
#pragma unroll
    for (int i = 0; i < 2; ++i)
#pragma unroll
      for (int j = 0; j < 4; ++j)
        acc[i][j] = __builtin_amdgcn_mfma_f32_16x16x32_bf16(af[i], bfr[j], acc[i][j], 0, 0, 0);
    __syncthreads();
  }

#pragma unroll
  for (int i = 0; i < 2; ++i) {
    const int rowb = m0 + wm * 32 + i * 16 + (lane >> 4) * 4;
#pragma unroll
    for (int j = 0; j < 4; ++j) {
      const int col = n0 + wn * 64 + j * 16 + fr;
#pragma unroll
      for (int r = 0; r < 4; ++r) {
        float v = acc[i][j][r];
        int rr = rowb + r;
        if (MODE == 0) {
          int b = rr >> 11, nq = rr & 2047, h = col >> 6, d = col & 63;
          float val = (v + bias[col]) * 0.180336884f;  // 0.125 * log2(e)
          obf[(((size_t)(b * H_ + h)) * NQ_ + nq) * 64 + d] = f2bf(val);
        } else if (MODE == 1) {
          int b = rr >> 11, nk = rr & 2047, h = col >> 6, d = col & 63;
          float gate = mem[b * NK_ + nk] * Wmm[col] + bmm[col];
          float val = (v + bias[col]) * gate;
          obf[(((size_t)(b * H_ + h)) * NK_ + nk) * 64 + d] = f2bf(val);
        } else if (MODE == 2) {
          int b = col >> 11, key = col & 2047, h = rr >> 6, d = rr & 63;
          float gate = mem[b * NK_ + key] * Wmm[rr] + bmm[rr];
          float val = (v + bias[rr]) * gate;
          obf[(((size_t)(b * H_ + h)) * 64 + d) * NK_ + key] = f2bf(val);
        } else {
          of32[(size_t)rr * DM_ + col] = v + bias[col];
        }
      }
    }
  }
}

// ---------------- flash attention v4: swapped QK^T, lane-local softmax ----------------
// 512 blocks x 8 waves; wave owns 16 q-rows; KV-tile 64; double-buffered LDS, 1 barrier/tile.
// S computed as mfma(K,Q) -> S[key][q=lane&15]: key-reduction is lane-local (no shfl storm).
__global__ __launch_bounds__(512, 4) void flash_attn(const unsigned short* __restrict__ Qp,
                                                     const unsigned short* __restrict__ Kp,
                                                     const unsigned short* __restrict__ VpT,
                                                     unsigned short* __restrict__ AO) {
  __shared__ unsigned short Ks[2][64][72];
  __shared__ unsigned short Vs[2][64][72];
  __shared__ __bf16 Ps[128][72];

  const int tid = threadIdx.x, lane = tid & 63, w = tid >> 6;
  // XCD-aware swizzle: 512 blocks % 8 == 0 -> bijective chunked remap
  const int gid = (blockIdx.x & 7) * 64 + (blockIdx.x >> 3);
  const int bh = gid >> 4;       // 0..31
  const int qt = gid & 15;       // 0..15, Q-tile of 128 rows
  const int fr = lane & 15, hi = lane >> 4, fk8 = hi * 8;
  const int w16 = w * 16;

  // Q fragments hoisted to registers (B-operand of swapped QK^T: col = q)
  const unsigned short* qg = Qp + (((size_t)bh * NQ_) + qt * 128 + w16 + fr) * 64;
  bf16x8 aq0 = *(const bf16x8*)&qg[fk8];
  bf16x8 aq1 = *(const bf16x8*)&qg[32 + fk8];

  // staging addresses: thread loads one u16x8 of K and one of V^T per tile
  const int srow = tid >> 3, scol = (tid & 7) * 8;
  const unsigned short* kg = Kp + ((size_t)bh * NK_ + srow) * 64 + scol;
  const unsigned short* vg = VpT + ((size_t)bh * 64 + srow) * NK_ + scol;

  f32x4 acc_o[4] = {};
  float m_run = -1e30f, l_run = 0.0f;

  // prologue: stage tile 0
  {
    u16x8 k0 = *(const u16x8*)kg;
    u16x8 v0 = *(const u16x8*)vg;
    *(u16x8*)&Ks[0][srow][scol] = k0;
    *(u16x8*)&Vs[0][srow][scol] = v0;
  }

  u16x8 kreg, vreg;
  for (int kt = 0; kt < 32; ++kt) {
    const int cur = kt & 1;
    if (kt + 1 < 32) {  // issue next-tile loads early (latency hides under compute)
      kreg = *(const u16x8*)(kg + (kt + 1) * 64 * 64);
      vreg = *(const u16x8*)(vg + (kt + 1) * 64);
    }
    __syncthreads();  // buf[cur] writes visible; prior reads of buf[cur^1] done

    // S[key][q] = K Q^T (swapped): A=K (rows=key), B=Q (cols=q)
    f32x4 sv[4];
    __builtin_amdgcn_s_setprio(1);
#pragma unroll
    for (int kk = 0; kk < 4; ++kk) {
      bf16x8 b0 = *(const bf16x8*)&Ks[cur][kk * 16 + fr][fk8];
      bf16x8 b1 = *(const bf16x8*)&Ks[cur][kk * 16 + fr][32 + fk8];
      f32x4 z = {0.f, 0.f, 0.f, 0.f};
      z = __builtin_amdgcn_mfma_f32_16x16x32_bf16(b0, aq0, z, 0, 0, 0);
      sv[kk] = __builtin_amdgcn_mfma_f32_16x16x32_bf16(b1, aq1, z, 0, 0, 0);
    }
    __builtin_amdgcn_s_setprio(0);
    // lane holds S[key = 16kk + 4hi + r][q = w16 + fr] -- 16 keys of this lane's q-row

    // lane-local max over 16 values, then combine across the 4 hi-groups
    float mx = fmaxf(fmaxf(sv[0][0], sv[0][1]), fmaxf(sv[0][2], sv[0][3]));
#pragma unroll
    for (int kk = 1; kk < 4; ++kk)
      mx = fmaxf(mx, fmaxf(fmaxf(sv[kk][0], sv[kk][1]), fmaxf(sv[kk][2], sv[kk][3])));
    mx = fmaxf(mx, __shfl_xor(mx, 16));
    mx = fmaxf(mx, __shfl_xor(mx, 32));

    if (__any(mx > m_run + 8.0f)) {  // defer-rescale: P bounded by 2^8
      float mnew = fmaxf(m_run, mx);
      float sc = __builtin_amdgcn_exp2f(m_run - mnew);
      m_run = mnew;
      l_run *= sc;
      // acc_o rows are q = w16 + 4*hi + r; fetch sc from the lane owning that q
#pragma unroll
      for (int r = 0; r < 4; ++r) {
        float scr = __shfl(sc, hi * 4 + r);
#pragma unroll
        for (int n = 0; n < 4; ++n) acc_o[n][r] *= scr;
      }
    }

    float ps = 0.0f;
#pragma unroll
    for (int kk = 0; kk < 4; ++kk) {
      float p0 = __builtin_amdgcn_exp2f(sv[kk][0] - m_run);
      float p1 = __builtin_amdgcn_exp2f(sv[kk][1] - m_run);
      float p2 = __builtin_amdgcn_exp2f(sv[kk][2] - m_run);
      float p3 = __builtin_amdgcn_exp2f(sv[kk][3] - m_run);
      ps += (p0 + p1) + (p2 + p3);
      u16x4 pk;
      pk[0] = __builtin_bit_cast(unsigned short, (__bf16)p0);
      pk[1] = __builtin_bit_cast(unsigned short, (__bf16)p1);
      pk[2] = __builtin_bit_cast(unsigned short, (__bf16)p2);
      pk[3] = __builtin_bit_cast(unsigned short, (__bf16)p3);
      // P[q = w16+fr][key = 16kk + 4hi + 0..3]: 4 consecutive cols -> one b64 write
      *(u16x4*)((unsigned short*)&Ps[w16 + fr][kk * 16 + hi * 4]) = pk;
    }
    ps += __shfl_xor(ps, 16);
    ps += __shfl_xor(ps, 32);
    l_run += ps;

    // O += P V' : P same-wave LDS (in-order, no barrier)
    __builtin_amdgcn_s_setprio(1);
#pragma unroll
    for (int ks = 0; ks < 2; ++ks) {
      bf16x8 pa = *(const bf16x8*)&Ps[w16 + fr][ks * 32 + fk8];
#pragma unroll
      for (int n = 0; n < 4; ++n) {
        bf16x8 vb = *(const bf16x8*)&Vs[cur][n * 16 + fr][ks * 32 + fk8];
        acc_o[n] = __builtin_amdgcn_mfma_f32_16x16x32_bf16(pa, vb, acc_o[n], 0, 0, 0);
      }
    }
    __builtin_amdgcn_s_setprio(0);

    if (kt + 1 < 32) {  // write next tile (compiler inserts vmcnt wait here)
      *(u16x8*)&Ks[cur ^ 1][srow][scol] = kreg;
      *(u16x8*)&Vs[cur ^ 1][srow][scol] = vreg;
    }
  }

  // epilogue: normalize, write AO (4096 x 1024 bf16)
  const int b = bh >> 4, h = bh & 15;
  float linv[4];
#pragma unroll
  for (int r = 0; r < 4; ++r) linv[r] = 1.0f / __shfl(l_run, hi * 4 + r);
#pragma unroll
  for (int n = 0; n < 4; ++n)
#pragma unroll
    for (int r = 0; r < 4; ++r) {
      float val = acc_o[n][r] * linv[r];
      int qrow = qt * 128 + w16 + hi * 4 + r;
      int col = h * 64 + n * 16 + fr;
      AO[(((size_t)b * NQ_ + qrow) << 10) + col] = f2bf(val);
    }
}

extern "C" void kernel_launch(void* const* d_in, const int* in_sizes, int n_in,
                              void* d_out, int out_size, void* d_ws, size_t ws_size,
                              hipStream_t stream) {
  const float* queries = (const float*)d_in[0];
  const float* keys    = (const float*)d_in[1];
  const float* values  = (const float*)d_in[2];
  const float* memory  = (const float*)d_in[3];
  const float* Wq  = (const float*)d_in[4];
  const float* bq  = (const float*)d_in[5];
  const float* Wk  = (const float*)d_in[6];
  const float* bk  = (const float*)d_in[7];
  const float* Wv  = (const float*)d_in[8];
  const float* bv  = (const float*)d_in[9];
  const float* Wo  = (const float*)d_in[10];
  const float* bo  = (const float*)d_in[11];
  const float* Wmm = (const float*)d_in[12];
  const float* bmm = (const float*)d_in[13];

  char* ws = (char*)d_ws;
  const size_t SZ_X = (size_t)4096 * 1024 * 2;  // 8 MiB bf16 4096x1024
  const size_t SZ_W = (size_t)1024 * 1024 * 2;  // 2 MiB bf16 1024x1024
  unsigned short* AO  = (unsigned short*)(ws);
  size_t off = SZ_X;
  unsigned short* WqT = (unsigned short*)(ws + off); off += SZ_W;
  unsigned short* WkT = (unsigned short*)(ws + off); off += SZ_W;
  unsigned short* WvT = (unsigned short*)(ws + off); off += SZ_W;
  unsigned short* WoT = (unsigned short*)(ws + off); off += SZ_W;
  unsigned short* Qp  = (unsigned short*)(ws + off); off += SZ_X;
  unsigned short* Kp  = (unsigned short*)(ws + off); off += SZ_X;
  unsigned short* VpT = (unsigned short*)(ws + off); off += SZ_X;

  transpose_cvt4<<<dim3(16, 16, 4), 256, 0, stream>>>(Wq, Wk, Wv, Wo, WqT, WkT, WvT, WoT);

  gemm_bf16<0><<<dim3(64, 8), 256, 0, stream>>>(queries, WqT, 1024, bq, nullptr, nullptr, nullptr, Qp, nullptr);
  gemm_bf16<1><<<dim3(64, 8), 256, 0, stream>>>(keys, WkT, 1024, bk, memory, Wmm, bmm, Kp, nullptr);
  gemm_bf16<2><<<dim3(16, 32), 256, 0, stream>>>(WvT, values, 1024, bv, memory, Wmm, bmm, VpT, nullptr);

  flash_attn<<<512, 512, 0, stream>>>(Qp, Kp, VpT, AO);

  gemm_bf16<3><<<dim3(64, 8), 256, 0, stream>>>(AO, WoT, 1024, bo, nullptr, nullptr, nullptr,
                                                nullptr, (float*)d_out);
}

// Round 5
// 144.044 us; speedup vs baseline: 3.3309x; 1.2739x over previous
//
#include <hip/hip_runtime.h>
#include <hip/hip_bf16.h>

#define H_   16
#define NQ_  2048
#define NK_  2048
#define DM_  1024

typedef float f32x4 __attribute__((ext_vector_type(4)));
typedef __bf16 bf16x8 __attribute__((ext_vector_type(8)));
typedef unsigned short u16x8 __attribute__((ext_vector_type(8)));

__device__ __forceinline__ unsigned short bfbits(float x) {
  __bf16 h = (__bf16)x;
  return __builtin_bit_cast(unsigned short, h);
}

// ---------------- prep: 4x fused transpose 1024x1024 f32 -> bf16 ----------------
__global__ __launch_bounds__(256) void transpose_cvt4(
    const float* __restrict__ s0, const float* __restrict__ s1,
    const float* __restrict__ s2, const float* __restrict__ s3,
    unsigned short* __restrict__ d0, unsigned short* __restrict__ d1,
    unsigned short* __restrict__ d2, unsigned short* __restrict__ d3) {
  const float* src = (blockIdx.z == 0) ? s0 : (blockIdx.z == 1) ? s1 : (blockIdx.z == 2) ? s2 : s3;
  unsigned short* dst = (blockIdx.z == 0) ? d0 : (blockIdx.z == 1) ? d1 : (blockIdx.z == 2) ? d2 : d3;
  __shared__ float t[64][65];
  const int r0 = blockIdx.x * 64, c0 = blockIdx.y * 64;
  for (int i = threadIdx.x; i < 4096; i += 256) {
    int r = i >> 6, c = i & 63;
    t[r][c] = src[(size_t)(r0 + r) * DM_ + c0 + c];
  }
  __syncthreads();
  for (int i = threadIdx.x; i < 4096; i += 256) {
    int n = i >> 6, k = i & 63;
    dst[(size_t)(c0 + n) * DM_ + r0 + k] = bfbits(t[k][n]);
  }
}

// ---------------- bf16 GEMM body, 64x128 tile, BK=32 ----------------
__device__ __forceinline__ void gll16(const unsigned short* g, unsigned short* l) {
  __builtin_amdgcn_global_load_lds((const __attribute__((address_space(1))) void*)g,
                                   (__attribute__((address_space(3))) void*)l, 16, 0, 0);
}

// MODE 0: Q proj (A=queries f32) -> Qp, val=(acc+bq)*0.125*log2e
// MODE 1: K proj (A=keys f32)    -> Kp, val=(acc+bk)*gate
// MODE 2: V proj^T (A=WvT bf16, Bt=values f32) -> VpT (key-cols permuted), val=(acc+bv)*gate
// MODE 3: out proj (A=AO bf16)   -> f32 d_out, val=acc+bo
template <int MODE>
__device__ __forceinline__ void gemm_body(
    int bx, int by,
    const void* __restrict__ Av, const void* __restrict__ Btv, int K,
    const float* __restrict__ bias, const float* __restrict__ mem,
    const float* __restrict__ Wmm, const float* __restrict__ bmm,
    unsigned short* __restrict__ obf, float* __restrict__ of32,
    unsigned short* Al, unsigned short* Bl) {
  constexpr bool AF32 = (MODE <= 1);
  constexpr bool BF32 = (MODE == 2);
  const int tid = threadIdx.x, lane = tid & 63, w = tid >> 6;
  const int wm = w >> 1, wn = w & 1;
  const int m0 = bx * 64, n0 = by * 128;
  const int lrow = lane >> 2, lcol = (lane & 3) * 8;
  const int fr = lane & 15, fk = (lane >> 4) * 8;

  f32x4 acc[2][4] = {};

  const size_t aoff = (size_t)(m0 + w * 16 + lrow) * K + lcol;
  const size_t boff = (size_t)(n0 + w * 32 + lrow) * K + lcol;
  const unsigned short* ag = (const unsigned short*)Av + aoff;
  const float*          agf = (const float*)Av + aoff;
  const unsigned short* bg = (const unsigned short*)Btv + boff;
  const float*          bgf = (const float*)Btv + boff;
  unsigned short* la0 = &Al[(w * 16) * 32];
  unsigned short* lawr = &Al[(w * 16 + lrow) * 32 + lcol];
  unsigned short* lb0 = &Bl[(w * 32) * 32];
  unsigned short* lb1 = &Bl[(w * 32 + 16) * 32];
  unsigned short* lbwr0 = &Bl[(w * 32 + lrow) * 32 + lcol];
  unsigned short* lbwr1 = &Bl[(w * 32 + 16 + lrow) * 32 + lcol];
  const size_t s16K = (size_t)16 * K;

  const int KT = K >> 5;
  for (int kt = 0; kt < KT; ++kt) {
    if constexpr (AF32) {
      float4 x0 = *(const float4*)agf;
      float4 x1 = *(const float4*)(agf + 4);
      agf += 32;
      bf16x8 o;
      o[0] = (__bf16)x0.x; o[1] = (__bf16)x0.y; o[2] = (__bf16)x0.z; o[3] = (__bf16)x0.w;
      o[4] = (__bf16)x1.x; o[5] = (__bf16)x1.y; o[6] = (__bf16)x1.z; o[7] = (__bf16)x1.w;
      *(bf16x8*)lawr = o;
    } else {
      gll16(ag, la0);
      ag += 32;
    }
    if constexpr (BF32) {
      float4 y0 = *(const float4*)bgf;
      float4 y1 = *(const float4*)(bgf + 4);
      float4 y2 = *(const float4*)(bgf + s16K);
      float4 y3 = *(const float4*)(bgf + s16K + 4);
      bgf += 32;
      bf16x8 o0, o1;
      o0[0] = (__bf16)y0.x; o0[1] = (__bf16)y0.y; o0[2] = (__bf16)y0.z; o0[3] = (__bf16)y0.w;
      o0[4] = (__bf16)y1.x; o0[5] = (__bf16)y1.y; o0[6] = (__bf16)y1.z; o0[7] = (__bf16)y1.w;
      o1[0] = (__bf16)y2.x; o1[1] = (__bf16)y2.y; o1[2] = (__bf16)y2.z; o1[3] = (__bf16)y2.w;
      o1[4] = (__bf16)y3.x; o1[5] = (__bf16)y3.y; o1[6] = (__bf16)y3.z; o1[7] = (__bf16)y3.w;
      *(bf16x8*)lbwr0 = o0;
      *(bf16x8*)lbwr1 = o1;
    } else {
      gll16(bg, lb0);
      gll16(bg + s16K, lb1);
      bg += 32;
    }
    __syncthreads();
    bf16x8 af[2], bfr[4];
#pragma unroll
    for (int i = 0; i < 2; ++i) af[i] = *(const bf16x8*)&Al[(wm * 32 + i * 16 + fr) * 32 + fk];
#pragma unroll
    for (int j = 0; j < 4; ++j) bfr[j] = *(const bf16x8*)&Bl[(wn * 64 + j * 16 + fr) * 32 + fk];
#pragma unroll
    for (int i = 0; i < 2; ++i)
#pragma unroll
      for (int j = 0; j < 4; ++j)
        acc[i][j] = __builtin_amdgcn_mfma_f32_16x16x32_bf16(af[i], bfr[j], acc[i][j], 0, 0, 0);
    __syncthreads();
  }

#pragma unroll
  for (int i = 0; i < 2; ++i) {
    const int rowb = m0 + wm * 32 + i * 16 + (lane >> 4) * 4;
#pragma unroll
    for (int j = 0; j < 4; ++j) {
      const int col = n0 + wn * 64 + j * 16 + fr;
#pragma unroll
      for (int r = 0; r < 4; ++r) {
        float v = acc[i][j][r];
        int rr = rowb + r;
        if (MODE == 0) {
          int b = rr >> 11, nq = rr & 2047, h = col >> 6, d = col & 63;
          float val = (v + bias[col]) * 0.180336884f;  // 0.125 * log2(e)
          obf[(((size_t)(b * H_ + h)) * NQ_ + nq) * 64 + d] = bfbits(val);
        } else if (MODE == 1) {
          int b = rr >> 11, nk = rr & 2047, h = col >> 6, d = col & 63;
          float gate = mem[b * NK_ + nk] * Wmm[col] + bmm[col];
          float val = (v + bias[col]) * gate;
          obf[(((size_t)(b * H_ + h)) * NK_ + nk) * 64 + d] = bfbits(val);
        } else if (MODE == 2) {
          int b = col >> 11, key = col & 2047, h = rr >> 6, d = rr & 63;
          float gate = mem[b * NK_ + key] * Wmm[rr] + bmm[rr];
          float val = (v + bias[rr]) * gate;
          // permute key columns within each 32-group so flash's PV A-frag is lane-local:
          // stored pos of actual key (bits: t=b4, h=b3:2, r=b1:0) = ks*32 + 8h + 4t + r
          int keyp = (key & ~31) | ((key & 12) << 1) | ((key & 16) >> 2) | (key & 3);
          obf[(((size_t)(b * H_ + h)) * 64 + d) * NK_ + keyp] = bfbits(val);
        } else {
          of32[(size_t)rr * DM_ + col] = v + bias[col];
        }
      }
    }
  }
}

// fused Q/K/V projections: one 1536-block launch (6 blocks/CU)
__global__ __launch_bounds__(256) void gemm_qkv(
    const float* __restrict__ queries, const float* __restrict__ keys,
    const unsigned short* __restrict__ WvT, const float* __restrict__ values,
    const unsigned short* __restrict__ WqT, const unsigned short* __restrict__ WkT,
    const float* __restrict__ bq, const float* __restrict__ bk, const float* __restrict__ bv,
    const float* __restrict__ mem, const float* __restrict__ Wmm, const float* __restrict__ bmm,
    unsigned short* __restrict__ Qp, unsigned short* __restrict__ Kp,
    unsigned short* __restrict__ VpT) {
  __shared__ unsigned short Al[64 * 32];
  __shared__ unsigned short Bl[128 * 32];
  // XCD-aware bijective swizzle (1536 % 8 == 0)
  const int b = (blockIdx.x & 7) * 192 + (blockIdx.x >> 3);
  if (b < 512) {
    gemm_body<0>(b & 63, b >> 6, queries, WqT, 1024, bq, nullptr, nullptr, nullptr,
                 Qp, nullptr, Al, Bl);
  } else if (b < 1024) {
    int bb = b - 512;
    gemm_body<1>(bb & 63, bb >> 6, keys, WkT, 1024, bk, mem, Wmm, bmm, Kp, nullptr, Al, Bl);
  } else {
    int bb = b - 1024;
    gemm_body<2>(bb & 15, bb >> 4, WvT, values, 1024, bv, mem, Wmm, bmm, VpT, nullptr, Al, Bl);
  }
}

// output projection
__global__ __launch_bounds__(256) void gemm_out(
    const unsigned short* __restrict__ AO, const unsigned short* __restrict__ WoT,
    const float* __restrict__ bo, float* __restrict__ out) {
  __shared__ unsigned short Al[64 * 32];
  __shared__ unsigned short Bl[128 * 32];
  const int b = (blockIdx.x & 7) * 64 + (blockIdx.x >> 3);
  gemm_body<3>(b & 63, b >> 6, AO, WoT, 1024, bo, nullptr, nullptr, nullptr,
               nullptr, out, Al, Bl);
}

// ---------------- flash attention v5: P fully in registers (own-lane PV frag) ----------------
// 512 blocks x 8 waves; wave owns 16 q-rows; KV-tile 64; double-buffered LDS, 1 barrier/tile.
// S = mfma(K,Q) -> S[key][q=fr]; PV A-frag j=4t+r <- p[2ks+t][r] (lane-local, V cols permuted).
__global__ __launch_bounds__(512, 6) void flash_attn(const unsigned short* __restrict__ Qp,
                                                     const unsigned short* __restrict__ Kp,
                                                     const unsigned short* __restrict__ VpT,
                                                     unsigned short* __restrict__ AO) {
  __shared__ unsigned short Ks[2][64][72];
  __shared__ unsigned short Vs[2][64][72];

  const int tid = threadIdx.x, lane = tid & 63, w = tid >> 6;
  // XCD-aware swizzle: 512 blocks % 8 == 0 -> bijective chunked remap
  const int gid = (blockIdx.x & 7) * 64 + (blockIdx.x >> 3);
  const int bh = gid >> 4;       // 0..31
  const int qt = gid & 15;       // 0..15, Q-tile of 128 rows
  const int fr = lane & 15, hi = lane >> 4, fk8 = hi * 8;
  const int w16 = w * 16;

  // Q fragments hoisted to registers (B-operand of swapped QK^T: col = q)
  const unsigned short* qg = Qp + (((size_t)bh * NQ_) + qt * 128 + w16 + fr) * 64;
  bf16x8 aq0 = *(const bf16x8*)&qg[fk8];
  bf16x8 aq1 = *(const bf16x8*)&qg[32 + fk8];

  // staging addresses: thread loads one u16x8 of K and one of V^T per tile
  const int srow = tid >> 3, scol = (tid & 7) * 8;
  const unsigned short* kg = Kp + ((size_t)bh * NK_ + srow) * 64 + scol;
  const unsigned short* vg = VpT + ((size_t)bh * 64 + srow) * NK_ + scol;

  f32x4 acc_o[4] = {};
  float m_run = -1e30f, l_run = 0.0f;

  // prologue: stage tile 0
  {
    u16x8 k0 = *(const u16x8*)kg;
    u16x8 v0 = *(const u16x8*)vg;
    *(u16x8*)&Ks[0][srow][scol] = k0;
    *(u16x8*)&Vs[0][srow][scol] = v0;
  }

  u16x8 kreg, vreg;
  for (int kt = 0; kt < 32; ++kt) {
    const int cur = kt & 1;
    if (kt + 1 < 32) {  // issue next-tile loads early (latency hides under compute)
      kreg = *(const u16x8*)(kg + (kt + 1) * 64 * 64);
      vreg = *(const u16x8*)(vg + (kt + 1) * 64);
    }
    __syncthreads();  // buf[cur] writes visible; prior reads of buf[cur^1] done

    // S[key][q] = K Q^T (swapped): A=K (rows=key), B=Q (cols=q)
    f32x4 sv[4];
    __builtin_amdgcn_s_setprio(1);
#pragma unroll
    for (int kk = 0; kk < 4; ++kk) {
      bf16x8 b0 = *(const bf16x8*)&Ks[cur][kk * 16 + fr][fk8];
      bf16x8 b1 = *(const bf16x8*)&Ks[cur][kk * 16 + fr][32 + fk8];
      f32x4 z = {0.f, 0.f, 0.f, 0.f};
      z = __builtin_amdgcn_mfma_f32_16x16x32_bf16(b0, aq0, z, 0, 0, 0);
      sv[kk] = __builtin_amdgcn_mfma_f32_16x16x32_bf16(b1, aq1, z, 0, 0, 0);
    }
    __builtin_amdgcn_s_setprio(0);
    // lane holds S[key = 16kk + 4hi + r][q = w16 + fr]

    // lane-local max over 16 keys, then combine across the 4 hi-groups
    float mx = fmaxf(fmaxf(sv[0][0], sv[0][1]), fmaxf(sv[0][2], sv[0][3]));
#pragma unroll
    for (int kk = 1; kk < 4; ++kk)
      mx = fmaxf(mx, fmaxf(fmaxf(sv[kk][0], sv[kk][1]), fmaxf(sv[kk][2], sv[kk][3])));
    mx = fmaxf(mx, __shfl_xor(mx, 16));
    mx = fmaxf(mx, __shfl_xor(mx, 32));

    if (__any(mx > m_run + 8.0f)) {  // defer-rescale: P bounded by 2^8
      float mnew = fmaxf(m_run, mx);
      float sc = __builtin_amdgcn_exp2f(m_run - mnew);
      m_run = mnew;
      l_run *= sc;
      // acc_o rows are q = w16 + 4*hi + r; fetch sc from the lane owning that q
#pragma unroll
      for (int r = 0; r < 4; ++r) {
        float scr = __shfl(sc, hi * 4 + r);
#pragma unroll
        for (int n = 0; n < 4; ++n) acc_o[n][r] *= scr;
      }
    }

    // P = exp2(S - m), packed directly into the two PV A-fragments (own-lane trick)
    float ps = 0.0f;
    bf16x8 pa0, pa1;
#pragma unroll
    for (int kk = 0; kk < 4; ++kk) {
#pragma unroll
      for (int r = 0; r < 4; ++r) {
        float pv = __builtin_amdgcn_exp2f(sv[kk][r] - m_run);
        ps += pv;
        if (kk < 2) pa0[(kk & 1) * 4 + r] = (__bf16)pv;
        else        pa1[(kk & 1) * 4 + r] = (__bf16)pv;
      }
    }
    ps += __shfl_xor(ps, 16);
    ps += __shfl_xor(ps, 32);
    l_run += ps;

    // O += P V' : P in registers; V cols pre-permuted so frag keys line up
    __builtin_amdgcn_s_setprio(1);
#pragma unroll
    for (int ks = 0; ks < 2; ++ks) {
      bf16x8 pa = ks ? pa1 : pa0;
#pragma unroll
      for (int n = 0; n < 4; ++n) {
        bf16x8 vb = *(const bf16x8*)&Vs[cur][n * 16 + fr][ks * 32 + fk8];
        acc_o[n] = __builtin_amdgcn_mfma_f32_16x16x32_bf16(pa, vb, acc_o[n], 0, 0, 0);
      }
    }
    __builtin_amdgcn_s_setprio(0);

    if (kt + 1 < 32) {  // write next tile (compiler inserts vmcnt wait here)
      *(u16x8*)&Ks[cur ^ 1][srow][scol] = kreg;
      *(u16x8*)&Vs[cur ^ 1][srow][scol] = vreg;
    }
  }

  // epilogue: normalize, write AO (4096 x 1024 bf16)
  const int b = bh >> 4, h = bh & 15;
  float linv[4];
#pragma unroll
  for (int r = 0; r < 4; ++r) linv[r] = 1.0f / __shfl(l_run, hi * 4 + r);
#pragma unroll
  for (int n = 0; n < 4; ++n)
#pragma unroll
    for (int r = 0; r < 4; ++r) {
      float val = acc_o[n][r] * linv[r];
      int qrow = qt * 128 + w16 + hi * 4 + r;
      int col = h * 64 + n * 16 + fr;
      AO[(((size_t)b * NQ_ + qrow) << 10) + col] = bfbits(val);
    }
}

extern "C" void kernel_launch(void* const* d_in, const int* in_sizes, int n_in,
                              void* d_out, int out_size, void* d_ws, size_t ws_size,
                              hipStream_t stream) {
  const float* queries = (const float*)d_in[0];
  const float* keys    = (const float*)d_in[1];
  const float* values  = (const float*)d_in[2];
  const float* memory  = (const float*)d_in[3];
  const float* Wq  = (const float*)d_in[4];
  const float* bq  = (const float*)d_in[5];
  const float* Wk  = (const float*)d_in[6];
  const float* bk  = (const float*)d_in[7];
  const float* Wv  = (const float*)d_in[8];
  const float* bv  = (const float*)d_in[9];
  const float* Wo  = (const float*)d_in[10];
  const float* bo  = (const float*)d_in[11];
  const float* Wmm = (const float*)d_in[12];
  const float* bmm = (const float*)d_in[13];

  char* ws = (char*)d_ws;
  const size_t SZ_X = (size_t)4096 * 1024 * 2;  // 8 MiB bf16 4096x1024
  const size_t SZ_W = (size_t)1024 * 1024 * 2;  // 2 MiB bf16 1024x1024
  unsigned short* AO  = (unsigned short*)(ws);
  size_t off = SZ_X;
  unsigned short* WqT = (unsigned short*)(ws + off); off += SZ_W;
  unsigned short* WkT = (unsigned short*)(ws + off); off += SZ_W;
  unsigned short* WvT = (unsigned short*)(ws + off); off += SZ_W;
  unsigned short* WoT = (unsigned short*)(ws + off); off += SZ_W;
  unsigned short* Qp  = (unsigned short*)(ws + off); off += SZ_X;
  unsigned short* Kp  = (unsigned short*)(ws + off); off += SZ_X;
  unsigned short* VpT = (unsigned short*)(ws + off); off += SZ_X;

  transpose_cvt4<<<dim3(16, 16, 4), 256, 0, stream>>>(Wq, Wk, Wv, Wo, WqT, WkT, WvT, WoT);

  gemm_qkv<<<1536, 256, 0, stream>>>(queries, keys, WvT, values, WqT, WkT,
                                     bq, bk, bv, memory, Wmm, bmm, Qp, Kp, VpT);

  flash_attn<<<512, 512, 0, stream>>>(Qp, Kp, VpT, AO);

  gemm_out<<<512, 256, 0, stream>>>(AO, WoT, bo, (float*)d_out);
}